// Round 16
// baseline (294.734 us; speedup 1.0000x reference)
//
#include <hip/hip_runtime.h>
#include <hip/hip_bf16.h>

typedef unsigned char u8;
typedef unsigned short u16;
typedef unsigned int u32;
typedef long long i64;
typedef __attribute__((ext_vector_type(8))) short bf16x8;
typedef __attribute__((ext_vector_type(4))) float f32x4;
typedef __attribute__((ext_vector_type(2))) float f32x2;

#define MAXDEG 64

// ---------- bf16 / fp8 helpers ----------
__device__ __forceinline__ u16 f2b(float f) {
    u32 u = __float_as_uint(f);
    u32 r = u + 0x7fffu + ((u >> 16) & 1u);   // round-to-nearest-even
    return (u16)(r >> 16);
}
__device__ __forceinline__ u8 f2e4m3(float f) {
    int p = __builtin_amdgcn_cvt_pk_fp8_f32(f, f, 0, false);
    return (u8)(p & 0xff);
}
// 4 consecutive fp8 (one u32) -> two f32x2 (HW cvt, stays packed)
__device__ __forceinline__ void load4f8v(const u8* p, f32x2& a, f32x2& b) {
    u32 q = *(const u32*)p;
    a = __builtin_amdgcn_cvt_pk_f32_fp8((int)q, false);
    b = __builtin_amdgcn_cvt_pk_f32_fp8((int)q, true);
}
__device__ __forceinline__ f32x2 vmax2(f32x2 a, f32x2 b) {
    return __builtin_elementwise_max(a, b);
}

// ---------- prep: conversions + copyR + zero cnt + index-storage detect ------
struct CJob { const float* in; void* out; int n4; int mode; };  // 0: ->bf16, 1: f32 copy
struct CJobs { CJob j[9]; };
__global__ __launch_bounds__(256) void prep_k(CJobs jobs, const u32* __restrict__ ei,
                                              int* __restrict__ flags,
                                              int* __restrict__ cnt, int N) {
    int y = blockIdx.y;
    int i = blockIdx.x * 256 + threadIdx.x;
    if (y < 9) {
        CJob job = jobs.j[y];
        if (i < job.n4) {
            float4 v = ((const float4*)job.in)[i];
            if (job.mode == 0) {
                ushort4 w;
                w.x = f2b(v.x); w.y = f2b(v.y); w.z = f2b(v.z); w.w = f2b(v.w);
                ((ushort4*)job.out)[i] = w;
            } else {
                ((float4*)job.out)[i] = v;
            }
        }
    } else {
        if (i < N) cnt[i] = 0;
        if (blockIdx.x == 0 && threadIdx.x < 64) {
            int lane = threadIdx.x;
            int oddZero = 0;
            for (int k = lane; k < 128; k += 64)
                if (ei[2 * k + 1] == 0) oddZero++;
#pragma unroll
            for (int o = 32; o > 0; o >>= 1) oddZero += __shfl_xor(oddZero, o, 64);
            if (lane == 0) flags[0] = (oddZero >= 126) ? 1 : 0;
        }
    }
}

// ---------- fused: edge bucket-build || layer-0 GEMM (+ both re tables) ----
// blocks [0, nbBuild): one thread per edge -> col[dst*64 + slot]
// blocks [nbBuild, +tilesN): X(bf16) @ {Wl0,Wr0} -> xlb,xrb (fp8)
// next 8 blocks: REL @ We0 -> reb0 ; next 8: REL @ We1 -> reb1
__global__ __launch_bounds__(256) void build_gemm_k(
    const void* __restrict__ ein, const void* __restrict__ rin,
    const int* __restrict__ flags, int* __restrict__ cnt,
    int2* __restrict__ col,
    const u16* __restrict__ x16, const u16* __restrict__ rel16,
    const u16* __restrict__ Wl0, const float* __restrict__ bl0,
    const u16* __restrict__ Wr0, const float* __restrict__ br0,
    const u16* __restrict__ We0, const u16* __restrict__ We1,
    u8* __restrict__ xlb, u8* __restrict__ xrb,
    u8* __restrict__ reb0, u8* __restrict__ reb1,
    int N, int E, int R, int nbBuild, int tilesN) {
    int b = blockIdx.x;
    if (b < nbBuild) {
        int i = b * 256 + threadIdx.x;
        if (i < E) {
            int f = flags[0];
            int s, d, r;
            if (f) {
                s = (int)((const i64*)ein)[i];
                d = (int)((const i64*)ein)[E + i];
                r = (int)((const i64*)rin)[i];
            } else {
                s = ((const int*)ein)[i];
                d = ((const int*)ein)[E + i];
                r = ((const int*)rin)[i];
            }
            s = max(0, min(s, N - 1));
            d = max(0, min(d, N - 1));
            r = max(0, min(r, R - 1));
            int slot = atomicAdd(&cnt[d], 1);
            if (slot < MAXDEG)
                col[(d << 6) + slot] = make_int2(s << 8, r << 8);  // pre-scaled
        }
        return;
    }
    int g = b - nbBuild;
    int wave = threadIdx.x >> 6, lane = threadIdx.x & 63;
    int m = lane & 15, quad = lane >> 4;

    const u16* in;
    const u16* WA;
    const u16* WB = nullptr;        // dual output if non-null
    const float* biasA = nullptr;
    const float* biasB = nullptr;
    u8* outA;
    u8* outB = nullptr;
    int rows, row0;
    if (g < tilesN) {
        in = x16; rows = N; row0 = g * 64 + wave * 16;
        WA = Wl0; biasA = bl0; outA = xlb;
        WB = Wr0; biasB = br0; outB = xrb;
    } else {
        int g2 = g - tilesN;        // 0..15
        int layer = g2 >> 3;
        in = rel16; rows = R; row0 = (g2 & 7) * 64 + wave * 16;
        WA = layer ? We1 : We0;
        outA = layer ? reb1 : reb0;
    }
    if (row0 >= rows) return;

    size_t row = (size_t)row0 + m;
    bf16x8 a0 = *(const bf16x8*)(in + row * 64 + quad * 8);
    bf16x8 a1 = *(const bf16x8*)(in + row * 64 + 32 + quad * 8);

    for (int ct = 0; ct < 16; ct++) {
        int n = ct * 16 + m;
        bf16x8 b0 = *(const bf16x8*)(WA + (size_t)n * 64 + quad * 8);
        bf16x8 b1 = *(const bf16x8*)(WA + (size_t)n * 64 + 32 + quad * 8);
        float bv = biasA ? biasA[n] : 0.f;
        f32x4 acc = {bv, bv, bv, bv};
        acc = __builtin_amdgcn_mfma_f32_16x16x32_bf16(a0, b0, acc, 0, 0, 0);
        acc = __builtin_amdgcn_mfma_f32_16x16x32_bf16(a1, b1, acc, 0, 0, 0);
#pragma unroll
        for (int i = 0; i < 4; i++)
            outA[(size_t)(row0 + quad * 4 + i) * 256 + n] = f2e4m3(acc[i]);
        if (WB) {
            bf16x8 c0 = *(const bf16x8*)(WB + (size_t)n * 64 + quad * 8);
            bf16x8 c1 = *(const bf16x8*)(WB + (size_t)n * 64 + 32 + quad * 8);
            float bv2 = biasB[n];
            f32x4 acc2 = {bv2, bv2, bv2, bv2};
            acc2 = __builtin_amdgcn_mfma_f32_16x16x32_bf16(a0, c0, acc2, 0, 0, 0);
            acc2 = __builtin_amdgcn_mfma_f32_16x16x32_bf16(a1, c1, acc2, 0, 0, 0);
#pragma unroll
            for (int i = 0; i < 4; i++)
                outB[(size_t)(row0 + quad * 4 + i) * 256 + n] = f2e4m3(acc2[i]);
        }
    }
}

// ---------- layer-1 GEMM (N rows): h0(bf16) @ {Wl1,Wr1} -> xlb,xrb ----------
__global__ __launch_bounds__(256) void gemm_n_k(
    const u16* __restrict__ Xin,
    const u16* __restrict__ Wl16, const float* __restrict__ bl,
    const u16* __restrict__ Wr16, const float* __restrict__ br,
    u8* __restrict__ xl, u8* __restrict__ xr, int N) {
    int wave = threadIdx.x >> 6, lane = threadIdx.x & 63;
    int row0 = blockIdx.x * 64 + wave * 16;
    if (row0 >= N) return;
    int m = lane & 15, quad = lane >> 4;
    size_t row = (size_t)row0 + m;
    bf16x8 a0 = *(const bf16x8*)(Xin + row * 64 + quad * 8);
    bf16x8 a1 = *(const bf16x8*)(Xin + row * 64 + 32 + quad * 8);

    for (int ct = 0; ct < 16; ct++) {
        int n = ct * 16 + m;
        bf16x8 b0 = *(const bf16x8*)(Wl16 + (size_t)n * 64 + quad * 8);
        bf16x8 b1 = *(const bf16x8*)(Wl16 + (size_t)n * 64 + 32 + quad * 8);
        float bv = bl[n];
        f32x4 acc = {bv, bv, bv, bv};
        acc = __builtin_amdgcn_mfma_f32_16x16x32_bf16(a0, b0, acc, 0, 0, 0);
        acc = __builtin_amdgcn_mfma_f32_16x16x32_bf16(a1, b1, acc, 0, 0, 0);
#pragma unroll
        for (int i = 0; i < 4; i++)
            xl[(size_t)(row0 + quad * 4 + i) * 256 + n] = f2e4m3(acc[i]);
        bf16x8 c0 = *(const bf16x8*)(Wr16 + (size_t)n * 64 + quad * 8);
        bf16x8 c1 = *(const bf16x8*)(Wr16 + (size_t)n * 64 + 32 + quad * 8);
        float bv2 = br[n];
        f32x4 acc2 = {bv2, bv2, bv2, bv2};
        acc2 = __builtin_amdgcn_mfma_f32_16x16x32_bf16(a0, c0, acc2, 0, 0, 0);
        acc2 = __builtin_amdgcn_mfma_f32_16x16x32_bf16(a1, c1, acc2, 0, 0, 0);
#pragma unroll
        for (int i = 0; i < 4; i++)
            xr[(size_t)(row0 + quad * 4 + i) * 256 + n] = f2e4m3(acc2[i]);
    }
}

// ---------- fused edge phase: wave per node, 8-edge unroll, fp8 tables ------
// lane: head h = lane>>4, channels ci..ci+3, ci = (lane&15)*4. Fixed-ref
// softmax, packed f32 math. 8 independent shfl chains + 16 gathers in flight
// per iteration (latency-bound loop -> ILP over residency).
__global__ __launch_bounds__(256) void edge_agg(
    const int* __restrict__ cnt, const int2* __restrict__ col,
    const u8* __restrict__ xl, const u8* __restrict__ xr,
    const u8* __restrict__ re,
    const float* __restrict__ att, const float* __restrict__ bias,
    u16* __restrict__ outB, float* __restrict__ outF, int writeF32, int N) {
    int node = blockIdx.x * 4 + (threadIdx.x >> 6);
    int lane = threadIdx.x & 63;
    if (node >= N) return;
    int h = lane >> 4;
    int ci = (lane & 15) * 4;
    u32 hoff = (u32)(h * 64 + ci);
    const u8* xlh = xl + hoff;     // per-lane table bases (col idx pre-scaled)
    const u8* xrh = xr + hoff;
    const u8* reh = re + hoff;

    f32x2 avA, avB;
    {
        float4 a4 = *(const float4*)(att + hoff);
        avA[0] = a4.x; avA[1] = a4.y; avB[0] = a4.z; avB[1] = a4.w;
    }
    f32x2 xlA, xlB, xrA, xrB;
    load4f8v(xlh + ((u32)node << 8), xlA, xlB);
    load4f8v(xrh + ((u32)node << 8), xrA, xrB);

    float l = 0.f;
    f32x2 accA = {0.f, 0.f}, accB = {0.f, 0.f};
    f32x2 meaA = {0.f, 0.f}, meaB = {0.f, 0.f};

    int degc = cnt[node];
    int deg = min(degc, MAXDEG);
    const int2* cb = col + ((u32)node << 6);
    int e = 0;

#define EDGE_MATH(xA, xB, vA, vB, tout)                \
    {                                                  \
        f32x2 mA = (xA + xrA) + vA;                    \
        f32x2 mB = (xB + xrB) + vB;                    \
        mA = vmax2(mA, mA * 0.2f);                     \
        mB = vmax2(mB, mB * 0.2f);                     \
        f32x2 tt = avA * mA + avB * mB;                \
        meaA += vA; meaB += vB;                        \
        tout = tt[0] + tt[1];                          \
    }

    // 8-edge unrolled main loop
    for (; e + 7 < deg; e += 8) {
        int4 q0 = *(const int4*)(cb + e);
        int4 q1 = *(const int4*)(cb + e + 2);
        int4 q2 = *(const int4*)(cb + e + 4);
        int4 q3 = *(const int4*)(cb + e + 6);
        f32x2 xA[8], xB[8], vA[8], vB[8];
        load4f8v(xlh + (u32)q0.x, xA[0], xB[0]);
        load4f8v(xlh + (u32)q0.z, xA[1], xB[1]);
        load4f8v(xlh + (u32)q1.x, xA[2], xB[2]);
        load4f8v(xlh + (u32)q1.z, xA[3], xB[3]);
        load4f8v(xlh + (u32)q2.x, xA[4], xB[4]);
        load4f8v(xlh + (u32)q2.z, xA[5], xB[5]);
        load4f8v(xlh + (u32)q3.x, xA[6], xB[6]);
        load4f8v(xlh + (u32)q3.z, xA[7], xB[7]);
        load4f8v(reh + (u32)q0.y, vA[0], vB[0]);
        load4f8v(reh + (u32)q0.w, vA[1], vB[1]);
        load4f8v(reh + (u32)q1.y, vA[2], vB[2]);
        load4f8v(reh + (u32)q1.w, vA[3], vB[3]);
        load4f8v(reh + (u32)q2.y, vA[4], vB[4]);
        load4f8v(reh + (u32)q2.w, vA[5], vB[5]);
        load4f8v(reh + (u32)q3.y, vA[6], vB[6]);
        load4f8v(reh + (u32)q3.w, vA[7], vB[7]);
        float t[8];
#pragma unroll
        for (int k = 0; k < 8; k++) {
            EDGE_MATH(xA[k], xB[k], vA[k], vB[k], t[k]);
        }
#pragma unroll
        for (int o = 1; o <= 8; o <<= 1) {
#pragma unroll
            for (int k = 0; k < 8; k++) t[k] += __shfl_xor(t[k], o, 64);
        }
        float p[8];
#pragma unroll
        for (int k = 0; k < 8; k++) p[k] = __expf(t[k]);
#pragma unroll
        for (int k = 0; k < 8; k++) {
            l += p[k];
            accA += xA[k] * p[k];
            accB += xB[k] * p[k];
        }
    }
    // 4-edge tail
    for (; e + 3 < deg; e += 4) {
        int2 c0 = cb[e], c1 = cb[e + 1], c2 = cb[e + 2], c3 = cb[e + 3];
        f32x2 x0A, x0B, x1A, x1B, x2A, x2B, x3A, x3B;
        f32x2 v0A, v0B, v1A, v1B, v2A, v2B, v3A, v3B;
        load4f8v(xlh + (u32)c0.x, x0A, x0B);
        load4f8v(xlh + (u32)c1.x, x1A, x1B);
        load4f8v(xlh + (u32)c2.x, x2A, x2B);
        load4f8v(xlh + (u32)c3.x, x3A, x3B);
        load4f8v(reh + (u32)c0.y, v0A, v0B);
        load4f8v(reh + (u32)c1.y, v1A, v1B);
        load4f8v(reh + (u32)c2.y, v2A, v2B);
        load4f8v(reh + (u32)c3.y, v3A, v3B);
        float t0, t1, t2, t3;
        EDGE_MATH(x0A, x0B, v0A, v0B, t0);
        EDGE_MATH(x1A, x1B, v1A, v1B, t1);
        EDGE_MATH(x2A, x2B, v2A, v2B, t2);
        EDGE_MATH(x3A, x3B, v3A, v3B, t3);
#pragma unroll
        for (int o = 1; o <= 8; o <<= 1) {
            t0 += __shfl_xor(t0, o, 64);
            t1 += __shfl_xor(t1, o, 64);
            t2 += __shfl_xor(t2, o, 64);
            t3 += __shfl_xor(t3, o, 64);
        }
        float p0 = __expf(t0), p1 = __expf(t1);
        float p2 = __expf(t2), p3 = __expf(t3);
        l += (p0 + p1) + (p2 + p3);
        accA += (x0A * p0 + x1A * p1) + (x2A * p2 + x3A * p3);
        accB += (x0B * p0 + x1B * p1) + (x2B * p2 + x3B * p3);
    }
    // scalar tail
    for (; e < deg; ++e) {
        int2 c0 = cb[e];
        f32x2 x0A, x0B, v0A, v0B;
        load4f8v(xlh + (u32)c0.x, x0A, x0B);
        load4f8v(reh + (u32)c0.y, v0A, v0B);
        float t0;
        EDGE_MATH(x0A, x0B, v0A, v0B, t0);
#pragma unroll
        for (int o = 1; o <= 8; o <<= 1) t0 += __shfl_xor(t0, o, 64);
        float p0 = __expf(t0);
        l += p0;
        accA += x0A * p0;
        accB += x0B * p0;
    }
#undef EDGE_MATH

    // self-loop LAST: m = xl[n] + xr[n] + mean(incoming re rows)
    {
        float inv_d = 1.0f / fmaxf((float)degc, 1.0f);
        f32x2 mA = (xlA + xrA) + meaA * inv_d;
        f32x2 mB = (xlB + xrB) + meaB * inv_d;
        mA = vmax2(mA, mA * 0.2f);
        mB = vmax2(mB, mB * 0.2f);
        f32x2 tt = avA * mA + avB * mB;
        float ts = tt[0] + tt[1];
#pragma unroll
        for (int o = 1; o <= 8; o <<= 1) ts += __shfl_xor(ts, o, 64);
        float ps = __expf(ts);
        l += ps;
        accA += xlA * ps;
        accB += xlB * ps;
    }

    float invl = 1.0f / l;
    float o0 = accA[0] * invl, o1 = accA[1] * invl;
    float o2 = accB[0] * invl, o3 = accB[1] * invl;
    // sum across the 4 head groups (lanes differing in bits 4,5)
    o0 += __shfl_xor(o0, 16, 64); o0 += __shfl_xor(o0, 32, 64);
    o1 += __shfl_xor(o1, 16, 64); o1 += __shfl_xor(o1, 32, 64);
    o2 += __shfl_xor(o2, 16, 64); o2 += __shfl_xor(o2, 32, 64);
    o3 += __shfl_xor(o3, 16, 64); o3 += __shfl_xor(o3, 32, 64);
    if (lane < 16) {
        float4 b4 = *(const float4*)(bias + ci);
        float r0 = o0 * 0.25f + b4.x;
        float r1 = o1 * 0.25f + b4.y;
        float r2 = o2 * 0.25f + b4.z;
        float r3 = o3 * 0.25f + b4.w;
        if (writeF32) {
            float4 w = {r0, r1, r2, r3};
            *(float4*)(outF + (size_t)node * 64 + ci) = w;
        } else {
            ushort4 w;
            w.x = f2b(r0); w.y = f2b(r1); w.z = f2b(r2); w.w = f2b(r3);
            *(ushort4*)(outB + (size_t)node * 64 + ci) = w;
        }
    }
}

// ---------- launch ----------
extern "C" void kernel_launch(void* const* d_in, const int* in_sizes, int n_in,
                              void* d_out, int out_size, void* d_ws, size_t ws_size,
                              hipStream_t stream) {
    const float* xf   = (const float*)d_in[0];
    const float* relf = (const float*)d_in[2];

    const int N = in_sizes[0] / 64;   // 20000
    const int E = in_sizes[3];        // 320000
    const int R = in_sizes[2] / 64;   // 512

    const float* Wl[2] = {(const float*)d_in[4],  (const float*)d_in[11]};
    const float* bl[2] = {(const float*)d_in[5],  (const float*)d_in[12]};
    const float* Wr[2] = {(const float*)d_in[6],  (const float*)d_in[13]};
    const float* br[2] = {(const float*)d_in[7],  (const float*)d_in[14]};
    const float* We[2] = {(const float*)d_in[8],  (const float*)d_in[15]};
    const float* at[2] = {(const float*)d_in[9],  (const float*)d_in[16]};
    const float* bb[2] = {(const float*)d_in[10], (const float*)d_in[17]};

    // workspace carve
    char* p = (char*)d_ws;
    auto alloc = [&](size_t bytes) -> void* {
        void* r = (void*)p;
        p += (bytes + 255) & ~(size_t)255;
        return r;
    };
    int* flags   = (int*)alloc(256);
    u16* x16     = (u16*)alloc((size_t)N * 64 * 2);
    u16* rel16   = (u16*)alloc((size_t)R * 64 * 2);
    u16* w16[6];
    for (int i = 0; i < 6; i++) w16[i] = (u16*)alloc((size_t)256 * 64 * 2);
    int* cnt     = (int*)alloc((size_t)N * 4);
    int2* col    = (int2*)alloc((size_t)N * MAXDEG * 8);
    u8* xlb  = (u8*)alloc((size_t)N * 256);
    u8* xrb  = (u8*)alloc((size_t)N * 256);
    u8* reb0 = (u8*)alloc((size_t)R * 256);
    u8* reb1 = (u8*)alloc((size_t)R * 256);
    u16* h0  = (u16*)alloc((size_t)N * 64 * 2);

    float* out = (float*)d_out;

    // 1. prep: conversions (+copyR), zero cnt, detect index storage
    CJobs jobs;
    jobs.j[0] = {xf,    x16,    N * 16,   0};
    jobs.j[1] = {relf,  rel16,  R * 16,   0};
    jobs.j[2] = {Wl[0], w16[0], 256 * 16, 0};
    jobs.j[3] = {Wr[0], w16[1], 256 * 16, 0};
    jobs.j[4] = {We[0], w16[2], 256 * 16, 0};
    jobs.j[5] = {Wl[1], w16[3], 256 * 16, 0};
    jobs.j[6] = {Wr[1], w16[4], 256 * 16, 0};
    jobs.j[7] = {We[1], w16[5], 256 * 16, 0};
    jobs.j[8] = {relf,  out + (size_t)N * 64, R * 16, 1};
    dim3 pgrid((N * 16 + 255) / 256, 10);
    prep_k<<<pgrid, 256, 0, stream>>>(jobs, (const u32*)d_in[1], flags, cnt, N);

    // 2. edge bucket-build || layer-0 GEMM (+ re tables for both layers)
    const int nbBuild = (E + 255) / 256;
    const int tilesN = (N + 63) / 64;
    build_gemm_k<<<nbBuild + tilesN + 16, 256, 0, stream>>>(
        d_in[1], d_in[3], flags, cnt, col, x16, rel16,
        w16[0], bl[0], w16[1], br[0], w16[2], w16[5],
        xlb, xrb, reb0, reb1, N, E, R, nbBuild, tilesN);

    // 3. layer-0 edge phase -> h0 (bf16)
    edge_agg<<<(N + 3) / 4, 256, 0, stream>>>(cnt, col, xlb, xrb, reb0,
                                              at[0], bb[0], h0, out, 0, N);

    // 4. layer-1 GEMM (N rows): h0 @ {Wl1,Wr1}
    gemm_n_k<<<tilesN, 256, 0, stream>>>(h0, w16[3], bl[1], w16[4], br[1],
                                         xlb, xrb, N);

    // 5. layer-1 edge phase -> out (f32)
    edge_agg<<<(N + 3) / 4, 256, 0, stream>>>(cnt, col, xlb, xrb, reb1,
                                              at[1], bb[1], h0, out, 1, N);
}

// Round 17
// 223.852 us; speedup vs baseline: 1.3166x; 1.3166x over previous
//
#include <hip/hip_runtime.h>
#include <hip/hip_bf16.h>

typedef unsigned char u8;
typedef unsigned short u16;
typedef unsigned int u32;
typedef long long i64;
typedef __attribute__((ext_vector_type(8))) short bf16x8;
typedef __attribute__((ext_vector_type(4))) float f32x4;
typedef __attribute__((ext_vector_type(2))) float f32x2;

#define MAXDEG 64

// ---------- bf16 / fp8 helpers ----------
__device__ __forceinline__ u16 f2b(float f) {
    u32 u = __float_as_uint(f);
    u32 r = u + 0x7fffu + ((u >> 16) & 1u);   // round-to-nearest-even
    return (u16)(r >> 16);
}
__device__ __forceinline__ u8 f2e4m3(float f) {
    int p = __builtin_amdgcn_cvt_pk_fp8_f32(f, f, 0, false);
    return (u8)(p & 0xff);
}
// 4 consecutive fp8 (one u32) -> two f32x2 (HW cvt, stays packed)
__device__ __forceinline__ void load4f8v(const u8* p, f32x2& a, f32x2& b) {
    u32 q = *(const u32*)p;
    a = __builtin_amdgcn_cvt_pk_f32_fp8((int)q, false);
    b = __builtin_amdgcn_cvt_pk_f32_fp8((int)q, true);
}
__device__ __forceinline__ f32x2 vmax2(f32x2 a, f32x2 b) {
    return __builtin_elementwise_max(a, b);
}
// 8 f32 -> bf16x8 (for MFMA A-operand from f32 source)
__device__ __forceinline__ bf16x8 cvt8bf(const float* p) {
    float b[8];
    *(float4*)b = *(const float4*)p;
    *(float4*)(b + 4) = *(const float4*)(p + 4);
    bf16x8 r;
#pragma unroll
    for (int j = 0; j < 8; j++) r[j] = (short)f2b(b[j]);
    return r;
}

// ---------- prep: small conversions + copyR + zero cnt + detect ----------
struct CJob { const float* in; void* out; int n4; int mode; };  // 0: ->bf16, 1: f32 copy
struct CJobs { CJob j[8]; };
__global__ __launch_bounds__(256) void prep_k(CJobs jobs, const u32* __restrict__ ei,
                                              int* __restrict__ flags,
                                              int* __restrict__ cnt, int N) {
    int y = blockIdx.y;
    int i = blockIdx.x * 256 + threadIdx.x;
    if (y < 8) {
        CJob job = jobs.j[y];
        if (i < job.n4) {
            float4 v = ((const float4*)job.in)[i];
            if (job.mode == 0) {
                ushort4 w;
                w.x = f2b(v.x); w.y = f2b(v.y); w.z = f2b(v.z); w.w = f2b(v.w);
                ((ushort4*)job.out)[i] = w;
            } else {
                ((float4*)job.out)[i] = v;
            }
        }
    } else {
        if (i < N) cnt[i] = 0;
        if (blockIdx.x == 0 && threadIdx.x < 64) {
            int lane = threadIdx.x;
            int oddZero = 0;
            for (int k = lane; k < 128; k += 64)
                if (ei[2 * k + 1] == 0) oddZero++;
#pragma unroll
            for (int o = 32; o > 0; o >>= 1) oddZero += __shfl_xor(oddZero, o, 64);
            if (lane == 0) flags[0] = (oddZero >= 126) ? 1 : 0;
        }
    }
}

// ---------- fused: edge bucket-build || layer-0 GEMM (+ both re tables) ----
// blocks [0, nbBuild): one thread per edge -> col[dst*64 + slot]
// blocks [nbBuild, +tilesN): Xf32 @ {Wl0,Wr0} -> xlb,xrb (fp8), in-reg bf16 cvt
// next 8 blocks: REL(bf16) @ We0 -> reb0 ; next 8: REL @ We1 -> reb1
__global__ __launch_bounds__(256) void build_gemm_k(
    const void* __restrict__ ein, const void* __restrict__ rin,
    const int* __restrict__ flags, int* __restrict__ cnt,
    int2* __restrict__ col,
    const float* __restrict__ xf, const u16* __restrict__ rel16,
    const u16* __restrict__ Wl0, const float* __restrict__ bl0,
    const u16* __restrict__ Wr0, const float* __restrict__ br0,
    const u16* __restrict__ We0, const u16* __restrict__ We1,
    u8* __restrict__ xlb, u8* __restrict__ xrb,
    u8* __restrict__ reb0, u8* __restrict__ reb1,
    int N, int E, int R, int nbBuild, int tilesN) {
    int b = blockIdx.x;
    if (b < nbBuild) {
        int i = b * 256 + threadIdx.x;
        if (i < E) {
            int f = flags[0];
            int s, d, r;
            if (f) {
                s = (int)((const i64*)ein)[i];
                d = (int)((const i64*)ein)[E + i];
                r = (int)((const i64*)rin)[i];
            } else {
                s = ((const int*)ein)[i];
                d = ((const int*)ein)[E + i];
                r = ((const int*)rin)[i];
            }
            s = max(0, min(s, N - 1));
            d = max(0, min(d, N - 1));
            r = max(0, min(r, R - 1));
            int slot = atomicAdd(&cnt[d], 1);
            if (slot < MAXDEG)
                col[(d << 6) + slot] = make_int2(s << 8, r << 8);  // pre-scaled
        }
        return;
    }
    int g = b - nbBuild;
    int wave = threadIdx.x >> 6, lane = threadIdx.x & 63;
    int m = lane & 15, quad = lane >> 4;

    const u16* WA;
    const u16* WB = nullptr;        // dual output if non-null
    const float* biasA = nullptr;
    const float* biasB = nullptr;
    u8* outA;
    u8* outB = nullptr;
    int rows, row0;
    bf16x8 a0, a1;
    if (g < tilesN) {
        rows = N; row0 = g * 64 + wave * 16;
        if (row0 >= rows) return;
        WA = Wl0; biasA = bl0; outA = xlb;
        WB = Wr0; biasB = br0; outB = xrb;
        size_t row = (size_t)row0 + m;
        a0 = cvt8bf(xf + row * 64 + quad * 8);
        a1 = cvt8bf(xf + row * 64 + 32 + quad * 8);
    } else {
        int g2 = g - tilesN;        // 0..15
        int layer = g2 >> 3;
        rows = R; row0 = (g2 & 7) * 64 + wave * 16;
        if (row0 >= rows) return;
        WA = layer ? We1 : We0;
        outA = layer ? reb1 : reb0;
        size_t row = (size_t)row0 + m;
        a0 = *(const bf16x8*)(rel16 + row * 64 + quad * 8);
        a1 = *(const bf16x8*)(rel16 + row * 64 + 32 + quad * 8);
    }

    for (int ct = 0; ct < 16; ct++) {
        int n = ct * 16 + m;
        bf16x8 b0 = *(const bf16x8*)(WA + (size_t)n * 64 + quad * 8);
        bf16x8 b1 = *(const bf16x8*)(WA + (size_t)n * 64 + 32 + quad * 8);
        float bv = biasA ? biasA[n] : 0.f;
        f32x4 acc = {bv, bv, bv, bv};
        acc = __builtin_amdgcn_mfma_f32_16x16x32_bf16(a0, b0, acc, 0, 0, 0);
        acc = __builtin_amdgcn_mfma_f32_16x16x32_bf16(a1, b1, acc, 0, 0, 0);
#pragma unroll
        for (int i = 0; i < 4; i++)
            outA[(size_t)(row0 + quad * 4 + i) * 256 + n] = f2e4m3(acc[i]);
        if (WB) {
            bf16x8 c0 = *(const bf16x8*)(WB + (size_t)n * 64 + quad * 8);
            bf16x8 c1 = *(const bf16x8*)(WB + (size_t)n * 64 + 32 + quad * 8);
            float bv2 = biasB[n];
            f32x4 acc2 = {bv2, bv2, bv2, bv2};
            acc2 = __builtin_amdgcn_mfma_f32_16x16x32_bf16(a0, c0, acc2, 0, 0, 0);
            acc2 = __builtin_amdgcn_mfma_f32_16x16x32_bf16(a1, c1, acc2, 0, 0, 0);
#pragma unroll
            for (int i = 0; i < 4; i++)
                outB[(size_t)(row0 + quad * 4 + i) * 256 + n] = f2e4m3(acc2[i]);
        }
    }
}

// ---------- layer-1 GEMM (N rows): h0(bf16) @ {Wl1,Wr1} -> xlb,xrb ----------
__global__ __launch_bounds__(256) void gemm_n_k(
    const u16* __restrict__ Xin,
    const u16* __restrict__ Wl16, const float* __restrict__ bl,
    const u16* __restrict__ Wr16, const float* __restrict__ br,
    u8* __restrict__ xl, u8* __restrict__ xr, int N) {
    int wave = threadIdx.x >> 6, lane = threadIdx.x & 63;
    int row0 = blockIdx.x * 64 + wave * 16;
    if (row0 >= N) return;
    int m = lane & 15, quad = lane >> 4;
    size_t row = (size_t)row0 + m;
    bf16x8 a0 = *(const bf16x8*)(Xin + row * 64 + quad * 8);
    bf16x8 a1 = *(const bf16x8*)(Xin + row * 64 + 32 + quad * 8);

    for (int ct = 0; ct < 16; ct++) {
        int n = ct * 16 + m;
        bf16x8 b0 = *(const bf16x8*)(Wl16 + (size_t)n * 64 + quad * 8);
        bf16x8 b1 = *(const bf16x8*)(Wl16 + (size_t)n * 64 + 32 + quad * 8);
        float bv = bl[n];
        f32x4 acc = {bv, bv, bv, bv};
        acc = __builtin_amdgcn_mfma_f32_16x16x32_bf16(a0, b0, acc, 0, 0, 0);
        acc = __builtin_amdgcn_mfma_f32_16x16x32_bf16(a1, b1, acc, 0, 0, 0);
#pragma unroll
        for (int i = 0; i < 4; i++)
            xl[(size_t)(row0 + quad * 4 + i) * 256 + n] = f2e4m3(acc[i]);
        bf16x8 c0 = *(const bf16x8*)(Wr16 + (size_t)n * 64 + quad * 8);
        bf16x8 c1 = *(const bf16x8*)(Wr16 + (size_t)n * 64 + 32 + quad * 8);
        float bv2 = br[n];
        f32x4 acc2 = {bv2, bv2, bv2, bv2};
        acc2 = __builtin_amdgcn_mfma_f32_16x16x32_bf16(a0, c0, acc2, 0, 0, 0);
        acc2 = __builtin_amdgcn_mfma_f32_16x16x32_bf16(a1, c1, acc2, 0, 0, 0);
#pragma unroll
        for (int i = 0; i < 4; i++)
            xr[(size_t)(row0 + quad * 4 + i) * 256 + n] = f2e4m3(acc2[i]);
    }
}

// ---------- fused edge phase: wave per node, 4-edge unroll, fp8 tables ------
// lane: head h = lane>>4, channels ci..ci+3, ci = (lane&15)*4. Fixed-ref
// softmax, packed f32 math (r12/r13 form — proven fastest across 5 variants).
__global__ __launch_bounds__(256) void edge_agg(
    const int* __restrict__ cnt, const int2* __restrict__ col,
    const u8* __restrict__ xl, const u8* __restrict__ xr,
    const u8* __restrict__ re,
    const float* __restrict__ att, const float* __restrict__ bias,
    u16* __restrict__ outB, float* __restrict__ outF, int writeF32, int N) {
    int node = blockIdx.x * 4 + (threadIdx.x >> 6);
    int lane = threadIdx.x & 63;
    if (node >= N) return;
    int h = lane >> 4;
    int ci = (lane & 15) * 4;
    u32 hoff = (u32)(h * 64 + ci);
    const u8* xlh = xl + hoff;     // per-lane table bases (col idx pre-scaled)
    const u8* xrh = xr + hoff;
    const u8* reh = re + hoff;

    f32x2 avA, avB;
    {
        float4 a4 = *(const float4*)(att + hoff);
        avA[0] = a4.x; avA[1] = a4.y; avB[0] = a4.z; avB[1] = a4.w;
    }
    f32x2 xlA, xlB, xrA, xrB;
    load4f8v(xlh + ((u32)node << 8), xlA, xlB);
    load4f8v(xrh + ((u32)node << 8), xrA, xrB);

    float l = 0.f;
    f32x2 accA = {0.f, 0.f}, accB = {0.f, 0.f};
    f32x2 meaA = {0.f, 0.f}, meaB = {0.f, 0.f};

    int degc = cnt[node];
    int deg = min(degc, MAXDEG);
    const int2* cb = col + ((u32)node << 6);
    int e = 0;

#define EDGE_MATH(xA, xB, vA, vB, tout)                \
    {                                                  \
        f32x2 mA = (xA + xrA) + vA;                    \
        f32x2 mB = (xB + xrB) + vB;                    \
        mA = vmax2(mA, mA * 0.2f);                     \
        mB = vmax2(mB, mB * 0.2f);                     \
        f32x2 tt = avA * mA + avB * mB;                \
        meaA += vA; meaB += vB;                        \
        tout = tt[0] + tt[1];                          \
    }

    for (; e + 3 < deg; e += 4) {
        int2 c0 = cb[e], c1 = cb[e + 1], c2 = cb[e + 2], c3 = cb[e + 3];
        f32x2 x0A, x0B, x1A, x1B, x2A, x2B, x3A, x3B;
        f32x2 v0A, v0B, v1A, v1B, v2A, v2B, v3A, v3B;
        load4f8v(xlh + (u32)c0.x, x0A, x0B);
        load4f8v(xlh + (u32)c1.x, x1A, x1B);
        load4f8v(xlh + (u32)c2.x, x2A, x2B);
        load4f8v(xlh + (u32)c3.x, x3A, x3B);
        load4f8v(reh + (u32)c0.y, v0A, v0B);
        load4f8v(reh + (u32)c1.y, v1A, v1B);
        load4f8v(reh + (u32)c2.y, v2A, v2B);
        load4f8v(reh + (u32)c3.y, v3A, v3B);
        float t0, t1, t2, t3;
        EDGE_MATH(x0A, x0B, v0A, v0B, t0);
        EDGE_MATH(x1A, x1B, v1A, v1B, t1);
        EDGE_MATH(x2A, x2B, v2A, v2B, t2);
        EDGE_MATH(x3A, x3B, v3A, v3B, t3);
#pragma unroll
        for (int o = 1; o <= 8; o <<= 1) {
            t0 += __shfl_xor(t0, o, 64);
            t1 += __shfl_xor(t1, o, 64);
            t2 += __shfl_xor(t2, o, 64);
            t3 += __shfl_xor(t3, o, 64);
        }
        float p0 = __expf(t0), p1 = __expf(t1);
        float p2 = __expf(t2), p3 = __expf(t3);
        l += (p0 + p1) + (p2 + p3);
        accA += (x0A * p0 + x1A * p1) + (x2A * p2 + x3A * p3);
        accB += (x0B * p0 + x1B * p1) + (x2B * p2 + x3B * p3);
    }
    for (; e < deg; ++e) {
        int2 c0 = cb[e];
        f32x2 x0A, x0B, v0A, v0B;
        load4f8v(xlh + (u32)c0.x, x0A, x0B);
        load4f8v(reh + (u32)c0.y, v0A, v0B);
        float t0;
        EDGE_MATH(x0A, x0B, v0A, v0B, t0);
#pragma unroll
        for (int o = 1; o <= 8; o <<= 1) t0 += __shfl_xor(t0, o, 64);
        float p0 = __expf(t0);
        l += p0;
        accA += x0A * p0;
        accB += x0B * p0;
    }
#undef EDGE_MATH

    // self-loop LAST: m = xl[n] + xr[n] + mean(incoming re rows)
    {
        float inv_d = 1.0f / fmaxf((float)degc, 1.0f);
        f32x2 mA = (xlA + xrA) + meaA * inv_d;
        f32x2 mB = (xlB + xrB) + meaB * inv_d;
        mA = vmax2(mA, mA * 0.2f);
        mB = vmax2(mB, mB * 0.2f);
        f32x2 tt = avA * mA + avB * mB;
        float ts = tt[0] + tt[1];
#pragma unroll
        for (int o = 1; o <= 8; o <<= 1) ts += __shfl_xor(ts, o, 64);
        float ps = __expf(ts);
        l += ps;
        accA += xlA * ps;
        accB += xlB * ps;
    }

    float invl = 1.0f / l;
    float o0 = accA[0] * invl, o1 = accA[1] * invl;
    float o2 = accB[0] * invl, o3 = accB[1] * invl;
    // sum across the 4 head groups (lanes differing in bits 4,5)
    o0 += __shfl_xor(o0, 16, 64); o0 += __shfl_xor(o0, 32, 64);
    o1 += __shfl_xor(o1, 16, 64); o1 += __shfl_xor(o1, 32, 64);
    o2 += __shfl_xor(o2, 16, 64); o2 += __shfl_xor(o2, 32, 64);
    o3 += __shfl_xor(o3, 16, 64); o3 += __shfl_xor(o3, 32, 64);
    if (lane < 16) {
        float4 b4 = *(const float4*)(bias + ci);
        float r0 = o0 * 0.25f + b4.x;
        float r1 = o1 * 0.25f + b4.y;
        float r2 = o2 * 0.25f + b4.z;
        float r3 = o3 * 0.25f + b4.w;
        if (writeF32) {
            float4 w = {r0, r1, r2, r3};
            *(float4*)(outF + (size_t)node * 64 + ci) = w;
        } else {
            ushort4 w;
            w.x = f2b(r0); w.y = f2b(r1); w.z = f2b(r2); w.w = f2b(r3);
            *(ushort4*)(outB + (size_t)node * 64 + ci) = w;
        }
    }
}

// ---------- launch ----------
extern "C" void kernel_launch(void* const* d_in, const int* in_sizes, int n_in,
                              void* d_out, int out_size, void* d_ws, size_t ws_size,
                              hipStream_t stream) {
    const float* xf   = (const float*)d_in[0];
    const float* relf = (const float*)d_in[2];

    const int N = in_sizes[0] / 64;   // 20000
    const int E = in_sizes[3];        // 320000
    const int R = in_sizes[2] / 64;   // 512

    const float* Wl[2] = {(const float*)d_in[4],  (const float*)d_in[11]};
    const float* bl[2] = {(const float*)d_in[5],  (const float*)d_in[12]};
    const float* Wr[2] = {(const float*)d_in[6],  (const float*)d_in[13]};
    const float* br[2] = {(const float*)d_in[7],  (const float*)d_in[14]};
    const float* We[2] = {(const float*)d_in[8],  (const float*)d_in[15]};
    const float* at[2] = {(const float*)d_in[9],  (const float*)d_in[16]};
    const float* bb[2] = {(const float*)d_in[10], (const float*)d_in[17]};

    // workspace carve
    char* p = (char*)d_ws;
    auto alloc = [&](size_t bytes) -> void* {
        void* r = (void*)p;
        p += (bytes + 255) & ~(size_t)255;
        return r;
    };
    int* flags   = (int*)alloc(256);
    u16* rel16   = (u16*)alloc((size_t)R * 64 * 2);
    u16* w16[6];
    for (int i = 0; i < 6; i++) w16[i] = (u16*)alloc((size_t)256 * 64 * 2);
    int* cnt     = (int*)alloc((size_t)N * 4);
    int2* col    = (int2*)alloc((size_t)N * MAXDEG * 8);
    u8* xlb  = (u8*)alloc((size_t)N * 256);
    u8* xrb  = (u8*)alloc((size_t)N * 256);
    u8* reb0 = (u8*)alloc((size_t)R * 256);
    u8* reb1 = (u8*)alloc((size_t)R * 256);
    u16* h0  = (u16*)alloc((size_t)N * 64 * 2);

    float* out = (float*)d_out;

    // 1. prep: small conversions (+copyR), zero cnt, detect index storage
    CJobs jobs;
    jobs.j[0] = {relf,  rel16,  R * 16,   0};
    jobs.j[1] = {Wl[0], w16[0], 256 * 16, 0};
    jobs.j[2] = {Wr[0], w16[1], 256 * 16, 0};
    jobs.j[3] = {We[0], w16[2], 256 * 16, 0};
    jobs.j[4] = {Wl[1], w16[3], 256 * 16, 0};
    jobs.j[5] = {Wr[1], w16[4], 256 * 16, 0};
    jobs.j[6] = {We[1], w16[5], 256 * 16, 0};
    jobs.j[7] = {relf,  out + (size_t)N * 64, R * 16, 1};
    dim3 pgrid((N + 255) / 256, 9);
    prep_k<<<pgrid, 256, 0, stream>>>(jobs, (const u32*)d_in[1], flags, cnt, N);

    // 2. edge bucket-build || layer-0 GEMM (+ re tables for both layers)
    const int nbBuild = (E + 255) / 256;
    const int tilesN = (N + 63) / 64;
    build_gemm_k<<<nbBuild + tilesN + 16, 256, 0, stream>>>(
        d_in[1], d_in[3], flags, cnt, col, xf, rel16,
        w16[0], bl[0], w16[1], br[0], w16[2], w16[5],
        xlb, xrb, reb0, reb1, N, E, R, nbBuild, tilesN);

    // 3. layer-0 edge phase -> h0 (bf16)
    edge_agg<<<(N + 3) / 4, 256, 0, stream>>>(cnt, col, xlb, xrb, reb0,
                                              at[0], bb[0], h0, out, 0, N);

    // 4. layer-1 GEMM (N rows): h0 @ {Wl1,Wr1}
    gemm_n_k<<<tilesN, 256, 0, stream>>>(h0, w16[3], bl[1], w16[4], br[1],
                                         xlb, xrb, N);

    // 5. layer-1 edge phase -> out (f32)
    edge_agg<<<(N + 3) / 4, 256, 0, stream>>>(cnt, col, xlb, xrb, reb1,
                                              at[1], bb[1], h0, out, 1, N);
}